// Round 8
// baseline (2862.490 us; speedup 1.0000x reference)
//
#include <hip/hip_runtime.h>
#include <hip/hip_bf16.h>

#define GN 50000
#define GE 800000
#define GH 4
#define GFH 32
#define GC 40
#define GIN 128

typedef __hip_bfloat16 bf16;

// mode m: 0 = tensor stored as bf16, 1 = stored as fp32
static __device__ __forceinline__ float ldx(const void* p, size_t i, int m) {
    if (m) return ((const float*)p)[i];
    return __bfloat162float(((const bf16*)p)[i]);
}
static __device__ __forceinline__ void stx(void* p, size_t i, int m, float v) {
    if (m) ((float*)p)[i] = v;
    else ((bf16*)p)[i] = __float2bfloat16(v);
}
static __device__ __forceinline__ unsigned short f2bfu(float v) {
    union { bf16 b; unsigned short u; } cv;
    cv.b = __float2bfloat16(v);
    return cv.u;
}
static __device__ __forceinline__ float guard_finite(float v) {
    if (!(v == v) || fabsf(v) > 1e30f) return 0.f;
    return v;
}

// ---------------- dtype probe: fp32 misread as bf16 shows wild exponents ----------------
__global__ void detect_kernel(const unsigned short* __restrict__ f, int* __restrict__ flag) {
    int t = threadIdx.x;  // 256
    unsigned short u = f[t];
    int e = (u >> 7) & 0xFF;
    if (e >= 0x8E) atomicAdd(flag, 1);  // |val| >= 2^15 or inf/nan -> not sane bf16 data
}

__global__ void sentinel_kernel(unsigned short* __restrict__ o, int n) {
    int i = blockIdx.x * blockDim.x + threadIdx.x;
    if (i < n) o[i] = 0x3F80;  // bf16 1.0
}

// ---------------- CSR build ----------------
__global__ void count_kernel(const int* __restrict__ dst, int* __restrict__ deg, int n) {
    int e = blockIdx.x * blockDim.x + threadIdx.x;
    if (e < n) {
        int d = dst[e];
        if (d >= 0 && d < GN) atomicAdd(&deg[d], 1);
    }
}

__global__ void scan_kernel(const int* __restrict__ deg, int* __restrict__ indptr,
                            int* __restrict__ cursor, int n) {
    __shared__ int buf[1024];
    int tid = threadIdx.x;
    int running = 0;
    for (int base = 0; base < n; base += 1024) {
        int i = base + tid;
        int v = (i < n) ? deg[i] : 0;
        buf[tid] = v;
        __syncthreads();
        for (int off = 1; off < 1024; off <<= 1) {
            int t = (tid >= off) ? buf[tid - off] : 0;
            __syncthreads();
            buf[tid] += t;
            __syncthreads();
        }
        int inc = buf[tid];
        if (i < n) { indptr[i + 1] = running + inc; cursor[i] = running + inc - v; }
        running += buf[1023];
        __syncthreads();
    }
    if (tid == 0) indptr[0] = 0;
}

__global__ void scatter_kernel(const int* __restrict__ src, const int* __restrict__ dst,
                               int* __restrict__ cursor, int* __restrict__ csr_src, int n) {
    int e = blockIdx.x * blockDim.x + threadIdx.x;
    if (e < n) {
        int d = dst[e];
        if (d < 0 || d >= GN) return;
        int p = atomicAdd(&cursor[d], 1);
        if (p >= 0 && p < GE) csr_src[p] = src[e];
    }
}

// ---------------- GEMM: Y[N,M](bf16) = X[N,128] @ W[128,M], fp32 acc ----------------
__global__ __launch_bounds__(256) void gemm_tile(const void* __restrict__ X, int xext,
                                                 const void* __restrict__ W,
                                                 bf16* __restrict__ Y, int nrows, int M,
                                                 const int* __restrict__ flag) {
    __shared__ float Xs[128][68];           // [k][r], pad to spread banks
    __shared__ unsigned short Ws[128][64];  // [k][c] bf16 bits
    int m = (*flag != 0) ? 1 : 0;
    int mx_ = xext ? m : 0;
    int tid = threadIdx.x;
    int rb = blockIdx.x * 64;
    int cb = blockIdx.y * 64;

    for (int idx = tid; idx < 64 * 128; idx += 256) {
        int r = idx >> 7, k = idx & 127;
        int row = rb + r;
        Xs[k][r] = (row < nrows) ? ldx(X, (size_t)row * 128 + k, mx_) : 0.f;
    }
    for (int idx = tid; idx < 128 * 64; idx += 256) {
        int k = idx >> 6, c = idx & 63;
        int col = cb + c;
        Ws[k][c] = (col < M) ? f2bfu(ldx(W, (size_t)k * M + col, m)) : (unsigned short)0;
    }
    __syncthreads();

    int cx = (tid & 15) << 2;
    int ry = (tid >> 4) << 2;
    float acc[4][4] = {};
#pragma unroll 4
    for (int k = 0; k < 128; k++) {
        float4 xv = *(const float4*)&Xs[k][ry];
        ushort4 wv = *(const ushort4*)&Ws[k][cx];
        float xs[4] = {xv.x, xv.y, xv.z, xv.w};
        float ws[4] = {__uint_as_float((unsigned)wv.x << 16), __uint_as_float((unsigned)wv.y << 16),
                       __uint_as_float((unsigned)wv.z << 16), __uint_as_float((unsigned)wv.w << 16)};
#pragma unroll
        for (int i = 0; i < 4; i++)
#pragma unroll
            for (int j = 0; j < 4; j++) acc[i][j] += xs[i] * ws[j];
    }
#pragma unroll
    for (int i = 0; i < 4; i++) {
        int row = rb + ry + i;
        if (row >= nrows) break;
#pragma unroll
        for (int j = 0; j < 4; j++) {
            int col = cb + cx + j;
            if (col < M) Y[(size_t)row * M + col] = __float2bfloat16(acc[i][j]);
        }
    }
}

// ---------------- in-place GEMM: X[nrows,128] <- X @ W[128,128] ----------------
// Each block owns 64 rows exclusively: stages them to LDS, then overwrites them.
__global__ __launch_bounds__(256) void gemm_inplace(bf16* __restrict__ X,
                                                    const void* __restrict__ W, int nrows,
                                                    const int* __restrict__ flag) {
    __shared__ float Xs[64][132];
    __shared__ unsigned short Ws[128][128];
    int m = (*flag != 0) ? 1 : 0;
    int tid = threadIdx.x;
    int rb = blockIdx.x * 64;

    for (int idx = tid; idx < 64 * 128; idx += 256) {
        int r = idx >> 7, k = idx & 127;
        int row = rb + r;
        Xs[r][k] = (row < nrows) ? __bfloat162float(X[(size_t)row * 128 + k]) : 0.f;
    }
    for (int idx = tid; idx < 128 * 128; idx += 256) {
        int k = idx >> 7, c = idx & 127;
        Ws[k][c] = f2bfu(ldx(W, (size_t)k * 128 + c, m));
    }
    __syncthreads();

    int cx = (tid & 31) << 2;  // 0..124
    int ry = (tid >> 5) << 3;  // 0..56
    float acc[8][4] = {};
    for (int k = 0; k < 128; k++) {
        float ws[4];
        ws[0] = __uint_as_float((unsigned)Ws[k][cx] << 16);
        ws[1] = __uint_as_float((unsigned)Ws[k][cx + 1] << 16);
        ws[2] = __uint_as_float((unsigned)Ws[k][cx + 2] << 16);
        ws[3] = __uint_as_float((unsigned)Ws[k][cx + 3] << 16);
#pragma unroll
        for (int i = 0; i < 8; i++) {
            float xv = Xs[ry + i][k];
#pragma unroll
            for (int j = 0; j < 4; j++) acc[i][j] += xv * ws[j];
        }
    }
#pragma unroll
    for (int i = 0; i < 8; i++) {
        int row = rb + ry + i;
        if (row >= nrows) break;
#pragma unroll
        for (int j = 0; j < 4; j++)
            X[(size_t)row * 128 + cx + j] = __float2bfloat16(acc[i][j]);
    }
}

// ---------------- el/er: [N,H] dot over F ----------------
__global__ void elr_kernel(const bf16* __restrict__ ft, const void* __restrict__ al,
                           const void* __restrict__ ar, float* __restrict__ el,
                           float* __restrict__ er, int n, int F, const int* __restrict__ flag) {
    int m = (*flag != 0) ? 1 : 0;
    int gid = blockIdx.x * blockDim.x + threadIdx.x;
    if (gid >= n * 4) return;
    int nid = gid >> 2, h = gid & 3;
    const bf16* f = ft + (size_t)nid * (4 * F) + h * F;
    float sl = 0.f, sr = 0.f;
    for (int i = 0; i < F; i++) {
        float v = __bfloat162float(f[i]);
        sl += v * ldx(al, h * F + i, m);
        sr += v * ldx(ar, h * F + i, m);
    }
    el[gid] = sl;
    er[gid] = sr;
}

// ---------------- per-dst softmax + aggregation ----------------
// skip_pre != nullptr: skip is precomputed (read own row v).  Else: fused matvec from h_in.
// out may alias skip_pre / h_in buffer: block v reads only row v, writes row v last.
template <int FTOT, bool FINAL>
__global__ __launch_bounds__(128) void agg_kernel(
    const bf16* __restrict__ ft, const float* __restrict__ el, const float* __restrict__ er,
    const int* __restrict__ indptr, const int* __restrict__ csr_src,
    const void* __restrict__ bias, const void* __restrict__ h_in, int hext,
    const void* __restrict__ w_lin, const bf16* __restrict__ skip_pre, bf16* __restrict__ out,
    const void* __restrict__ bias_last, void* __restrict__ fout,
    const int* __restrict__ flag) {
    constexpr int F = FTOT / 4;
    constexpr int CH = 128;
    int m = (*flag != 0) ? 1 : 0;
    int mh = hext ? m : 0;
    int v = blockIdx.x;
    int t = threadIdx.x;
    int beg = indptr[v], end = indptr[v + 1];
    beg = max(0, min(beg, GE));
    end = max(beg, min(end, GE));

    __shared__ float hv[128];
    __shared__ float wbuf[CH * 4];
    __shared__ int ubuf[CH];
    __shared__ float red[128];
    __shared__ float s_sh[4];
    __shared__ float ovals[FINAL ? 160 : 1];
    __shared__ float lsm[FINAL ? 64 : 1];

    float sk0 = 0.f, sk1 = 0.f;
    if (skip_pre != nullptr) {
        sk0 = __bfloat162float(skip_pre[(size_t)v * FTOT + t]);
    } else {
        hv[t] = ldx(h_in, (size_t)v * 128 + t, mh);
        __syncthreads();
        // skip = h[v] @ w_lin; uniform dtype branch hoisted out of the loop, unroll x4
        if (m == 0) {
            const bf16* wl = (const bf16*)w_lin;
            float p0 = 0.f, p1 = 0.f, p2 = 0.f, p3 = 0.f;
            float q0 = 0.f, q1 = 0.f, q2 = 0.f, q3 = 0.f;
            for (int k = 0; k < 128; k += 4) {
                float h0 = hv[k], h1 = hv[k + 1], h2 = hv[k + 2], h3 = hv[k + 3];
                p0 += h0 * __bfloat162float(wl[(size_t)k * FTOT + t]);
                p1 += h1 * __bfloat162float(wl[(size_t)(k + 1) * FTOT + t]);
                p2 += h2 * __bfloat162float(wl[(size_t)(k + 2) * FTOT + t]);
                p3 += h3 * __bfloat162float(wl[(size_t)(k + 3) * FTOT + t]);
                if (FTOT > 128 && t < FTOT - 128) {
                    q0 += h0 * __bfloat162float(wl[(size_t)k * FTOT + 128 + t]);
                    q1 += h1 * __bfloat162float(wl[(size_t)(k + 1) * FTOT + 128 + t]);
                    q2 += h2 * __bfloat162float(wl[(size_t)(k + 2) * FTOT + 128 + t]);
                    q3 += h3 * __bfloat162float(wl[(size_t)(k + 3) * FTOT + 128 + t]);
                }
            }
            sk0 = (p0 + p1) + (p2 + p3);
            sk1 = (q0 + q1) + (q2 + q3);
        } else {
            for (int k = 0; k < 128; k++) {
                float hk = hv[k];
                sk0 += hk * ldx(w_lin, (size_t)k * FTOT + t, m);
                if (FTOT > 128 && t < FTOT - 128)
                    sk1 += hk * ldx(w_lin, (size_t)k * FTOT + 128 + t, m);
            }
        }
    }

    int h = t & 3, slot = t >> 2;
    float erv = er[v * 4 + h];
    float s_part = 0.f, acc0 = 0.f, acc1 = 0.f;
    int h0 = t / F;

    for (int cb = beg; cb < end; cb += CH) {
        int chn = min(CH, end - cb);
        for (int j = slot; j < chn; j += 32) {
            int u = csr_src[cb + j];
            u = min(max(u, 0), GN - 1);
            if (h == 0) ubuf[j] = u;
            float e = el[u * 4 + h] + erv;
            e = e > 0.f ? e : 0.2f * e;
            float w = __expf(fminf(e, 60.f));
            wbuf[j * 4 + h] = w;
            s_part += w;
        }
        __syncthreads();
        // gather: unroll x4 with independent partial accumulators (4 loads in flight)
        {
            float a0 = 0.f, a1 = 0.f, a2 = 0.f, a3 = 0.f;
            float b0 = 0.f, b1 = 0.f, b2 = 0.f, b3 = 0.f;
            int j = 0;
            for (; j + 4 <= chn; j += 4) {
                int u0 = ubuf[j], u1 = ubuf[j + 1], u2 = ubuf[j + 2], u3 = ubuf[j + 3];
                float w0 = wbuf[j * 4 + h0], w1 = wbuf[(j + 1) * 4 + h0];
                float w2 = wbuf[(j + 2) * 4 + h0], w3 = wbuf[(j + 3) * 4 + h0];
                float f0 = __bfloat162float(ft[(size_t)u0 * FTOT + t]);
                float f1 = __bfloat162float(ft[(size_t)u1 * FTOT + t]);
                float f2 = __bfloat162float(ft[(size_t)u2 * FTOT + t]);
                float f3 = __bfloat162float(ft[(size_t)u3 * FTOT + t]);
                a0 += w0 * f0;
                a1 += w1 * f1;
                a2 += w2 * f2;
                a3 += w3 * f3;
                if (FTOT > 128 && t < FTOT - 128) {
                    float g0 = __bfloat162float(ft[(size_t)u0 * FTOT + 128 + t]);
                    float g1 = __bfloat162float(ft[(size_t)u1 * FTOT + 128 + t]);
                    float g2 = __bfloat162float(ft[(size_t)u2 * FTOT + 128 + t]);
                    float g3 = __bfloat162float(ft[(size_t)u3 * FTOT + 128 + t]);
                    b0 += wbuf[j * 4 + 3] * g0;
                    b1 += wbuf[(j + 1) * 4 + 3] * g1;
                    b2 += wbuf[(j + 2) * 4 + 3] * g2;
                    b3 += wbuf[(j + 3) * 4 + 3] * g3;
                }
            }
            for (; j < chn; j++) {
                int u = ubuf[j];
                const bf16* fu = ft + (size_t)u * FTOT;
                a0 += wbuf[j * 4 + h0] * __bfloat162float(fu[t]);
                if (FTOT > 128 && t < FTOT - 128)
                    b0 += wbuf[j * 4 + 3] * __bfloat162float(fu[128 + t]);
            }
            acc0 += (a0 + a1) + (a2 + a3);
            if (FTOT > 128) acc1 += (b0 + b1) + (b2 + b3);
        }
        __syncthreads();
    }

    red[t] = s_part;
    __syncthreads();
    for (int off = 64; off >= 4; off >>= 1) {
        if (t < off) red[t] += red[t + off];
        __syncthreads();
    }
    if (t < 4) s_sh[t] = red[t];
    __syncthreads();

    float s0 = s_sh[h0];
    float r0 = (s0 > 0.f) ? acc0 / s0 : 0.f;
    float o0 = r0 + ldx(bias, t, m) + sk0;
    float o1 = 0.f;
    if (FTOT > 128 && t < FTOT - 128) {
        float s1 = s_sh[3];
        float r1 = (s1 > 0.f) ? acc1 / s1 : 0.f;
        o1 = r1 + ldx(bias, 128 + t, m) + sk1;
    }

    if constexpr (!FINAL) {
        out[(size_t)v * FTOT + t] = __float2bfloat16(guard_finite(o0));
    } else {
        ovals[t] = o0;
        if (t < 32) ovals[128 + t] = o1;
        __syncthreads();
        if (t < 40)
            lsm[t] = 0.25f * (ovals[t] + ovals[40 + t] + ovals[80 + t] + ovals[120 + t]) +
                     ldx(bias_last, t, m);
        __syncthreads();
        if (t < 64) {
            float x = (t < 40) ? lsm[t] : -3.0e38f;
            float mx = x;
            for (int off = 1; off < 64; off <<= 1) mx = fmaxf(mx, __shfl_xor(mx, off));
            float ex = (t < 40) ? __expf(x - mx) : 0.f;
            float sum = ex;
            for (int off = 1; off < 64; off <<= 1) sum += __shfl_xor(sum, off);
            if (t < 40) stx(fout, (size_t)v * 40 + t, m, guard_finite(x - mx - __logf(sum)));
        }
    }
}

// ---------------- BatchNorm (+ ReLU) on bf16 [N,128] ----------------
__global__ void bn_stats(const bf16* __restrict__ x, float* __restrict__ gsum,
                         float* __restrict__ gsq, int n) {
    int c = threadIdx.x;  // 128
    int rows_per_block = (n + gridDim.x - 1) / gridDim.x;
    int r0 = blockIdx.x * rows_per_block;
    int r1 = min(n, r0 + rows_per_block);
    float s = 0.f, q = 0.f;
    for (int r = r0; r < r1; r++) {
        float v = __bfloat162float(x[(size_t)r * 128 + c]);
        s += v;
        q += v * v;
    }
    atomicAdd(&gsum[c], s);
    atomicAdd(&gsq[c], q);
}

__global__ void bn_apply(bf16* __restrict__ x, const float* __restrict__ gsum,
                         const float* __restrict__ gsq, const void* __restrict__ g,
                         const void* __restrict__ be, int n, const int* __restrict__ flag) {
    int m = (*flag != 0) ? 1 : 0;
    int gid = blockIdx.x * blockDim.x + threadIdx.x;
    if (gid >= n * 128) return;
    int c = gid & 127;
    float inv_n = 1.f / (float)n;
    float mu = gsum[c] * inv_n;
    float var = gsq[c] * inv_n - mu * mu;
    float y = (__bfloat162float(x[gid]) - mu) * rsqrtf(fmaxf(var, 0.f) + 1e-5f) * ldx(g, c, m) +
              ldx(be, c, m);
    x[gid] = __float2bfloat16(y > 0.f ? y : 0.f);
}

extern "C" void kernel_launch(void* const* d_in, const int* in_sizes, int n_in,
                              void* d_out, int out_size, void* d_ws, size_t ws_size,
                              hipStream_t stream) {
    const void* feat = d_in[0];
    const int* src = (const int*)d_in[1];
    const int* dst = (const int*)d_in[2];
    const void* w_fc0 = d_in[3];
    const void* al0 = d_in[4];
    const void* ar0 = d_in[5];
    const void* b0 = d_in[6];
    const void* w_lin0 = d_in[7];
    const void* g0 = d_in[8];
    const void* be0 = d_in[9];
    const void* w_fc1 = d_in[10];
    const void* al1 = d_in[11];
    const void* ar1 = d_in[12];
    const void* b1 = d_in[13];
    const void* w_lin1 = d_in[14];
    const void* g1 = d_in[15];
    const void* be1 = d_in[16];
    const void* w_fc2 = d_in[17];
    const void* al2 = d_in[18];
    const void* ar2 = d_in[19];
    const void* b2 = d_in[20];
    const void* w_lin2 = d_in[21];
    const void* bias_last = d_in[22];

    // ---- workspace guard: total need ~34.3 MB ----
    if (ws_size < 35000000) {
        sentinel_kernel<<<(out_size + 255) / 256, 256, 0, stream>>>((unsigned short*)d_out,
                                                                    out_size);
        return;
    }

    char* p = (char*)d_ws;
    auto alloc = [&](size_t bytes) {
        char* r = p;
        p += (bytes + 255) & ~(size_t)255;
        return r;
    };
    bf16* ftb = (bf16*)alloc((size_t)GN * 160 * 2);   // 16.0 MB
    bf16* hbuf = (bf16*)alloc((size_t)GN * 128 * 2);  // 12.8 MB
    float* elb = (float*)alloc((size_t)GN * 4 * 4);   // 0.8 MB
    float* erb = (float*)alloc((size_t)GN * 4 * 4);   // 0.8 MB
    int* indptr = (int*)alloc((size_t)(GN + 1) * 4);
    int* cursor = (int*)alloc((size_t)GN * 4);
    char* zbase = p;  // ---- zero-initialized region ----
    int* deg = (int*)alloc((size_t)GN * 4);
    int* csr = (int*)alloc((size_t)GE * 4);  // 3.2 MB
    float* gs0 = (float*)alloc(128 * 4);
    float* gq0 = (float*)alloc(128 * 4);
    float* gs1 = (float*)alloc(128 * 4);
    float* gq1 = (float*)alloc(128 * 4);
    int* flag = (int*)alloc(4);
    hipMemsetAsync(zbase, 0, (size_t)(p - zbase), stream);

    detect_kernel<<<1, 256, 0, stream>>>((const unsigned short*)feat, flag);

    // CSR build
    count_kernel<<<(GE + 255) / 256, 256, 0, stream>>>(dst, deg, GE);
    scan_kernel<<<1, 1024, 0, stream>>>(deg, indptr, cursor, GN);
    scatter_kernel<<<(GE + 255) / 256, 256, 0, stream>>>(src, dst, cursor, csr, GE);

    dim3 g2(782, 2), g3(782, 3);

    // ----- Layer 0 -----
    gemm_tile<<<g2, 256, 0, stream>>>(feat, 1, w_fc0, ftb, GN, 128, flag);
    gemm_tile<<<g2, 256, 0, stream>>>(feat, 1, w_lin0, hbuf, GN, 128, flag);  // skip0 -> hbuf
    elr_kernel<<<(GN * 4 + 255) / 256, 256, 0, stream>>>(ftb, al0, ar0, elb, erb, GN, 32, flag);
    agg_kernel<128, false><<<GN, 128, 0, stream>>>(ftb, elb, erb, indptr, csr, b0, feat, 1,
                                                   w_lin0, hbuf, hbuf, nullptr, nullptr, flag);
    bn_stats<<<256, 128, 0, stream>>>(hbuf, gs0, gq0, GN);
    bn_apply<<<(GN * 128 + 255) / 256, 256, 0, stream>>>(hbuf, gs0, gq0, g0, be0, GN, flag);

    // ----- Layer 1 (h updated in place) -----
    gemm_tile<<<g2, 256, 0, stream>>>(hbuf, 0, w_fc1, ftb, GN, 128, flag);
    elr_kernel<<<(GN * 4 + 255) / 256, 256, 0, stream>>>(ftb, al1, ar1, elb, erb, GN, 32, flag);
    gemm_inplace<<<782, 256, 0, stream>>>(hbuf, w_lin1, GN, flag);  // hbuf <- h1 @ w_lin1
    agg_kernel<128, false><<<GN, 128, 0, stream>>>(ftb, elb, erb, indptr, csr, b1, hbuf, 0,
                                                   w_lin1, hbuf, hbuf, nullptr, nullptr, flag);
    bn_stats<<<256, 128, 0, stream>>>(hbuf, gs1, gq1, GN);
    bn_apply<<<(GN * 128 + 255) / 256, 256, 0, stream>>>(hbuf, gs1, gq1, g1, be1, GN, flag);

    // ----- Layer 2 (final; skip matvec kept in-kernel, now unrolled) -----
    gemm_tile<<<g3, 256, 0, stream>>>(hbuf, 0, w_fc2, ftb, GN, 160, flag);
    elr_kernel<<<(GN * 4 + 255) / 256, 256, 0, stream>>>(ftb, al2, ar2, elb, erb, GN, 40, flag);
    agg_kernel<160, true><<<GN, 128, 0, stream>>>(ftb, elb, erb, indptr, csr, b2, hbuf, 0,
                                                  w_lin2, nullptr, nullptr, bias_last, d_out,
                                                  flag);
}

// Round 9
// 1295.873 us; speedup vs baseline: 2.2089x; 2.2089x over previous
//
#include <hip/hip_runtime.h>
#include <hip/hip_bf16.h>

#define GN 50000
#define GE 800000
#define GH 4
#define GFH 32
#define GC 40
#define GIN 128

typedef __hip_bfloat16 bf16;

// mode m: 0 = tensor stored as bf16, 1 = stored as fp32
static __device__ __forceinline__ float ldx(const void* p, size_t i, int m) {
    if (m) return ((const float*)p)[i];
    return __bfloat162float(((const bf16*)p)[i]);
}
static __device__ __forceinline__ void stx(void* p, size_t i, int m, float v) {
    if (m) ((float*)p)[i] = v;
    else ((bf16*)p)[i] = __float2bfloat16(v);
}
static __device__ __forceinline__ unsigned short f2bfu(float v) {
    union { bf16 b; unsigned short u; } cv;
    cv.b = __float2bfloat16(v);
    return cv.u;
}
static __device__ __forceinline__ float lo16(unsigned u) { return __uint_as_float(u << 16); }
static __device__ __forceinline__ float hi16(unsigned u) { return __uint_as_float(u & 0xFFFF0000u); }
static __device__ __forceinline__ float guard_finite(float v) {
    if (!(v == v) || fabsf(v) > 1e30f) return 0.f;
    return v;
}

// ---------------- dtype probe: fp32 misread as bf16 shows wild exponents ----------------
__global__ void detect_kernel(const unsigned short* __restrict__ f, int* __restrict__ flag) {
    int t = threadIdx.x;  // 256
    unsigned short u = f[t];
    int e = (u >> 7) & 0xFF;
    if (e >= 0x8E) atomicAdd(flag, 1);  // |val| >= 2^15 or inf/nan -> not sane bf16 data
}

__global__ void sentinel_kernel(unsigned short* __restrict__ o, int n) {
    int i = blockIdx.x * blockDim.x + threadIdx.x;
    if (i < n) o[i] = 0x3F80;  // bf16 1.0
}

// ---------------- CSR build ----------------
__global__ void count_kernel(const int* __restrict__ dst, int* __restrict__ deg, int n) {
    int e = blockIdx.x * blockDim.x + threadIdx.x;
    if (e < n) {
        int d = dst[e];
        if (d >= 0 && d < GN) atomicAdd(&deg[d], 1);
    }
}

__global__ void scan_kernel(const int* __restrict__ deg, int* __restrict__ indptr,
                            int* __restrict__ cursor, int n) {
    __shared__ int buf[1024];
    int tid = threadIdx.x;
    int running = 0;
    for (int base = 0; base < n; base += 1024) {
        int i = base + tid;
        int v = (i < n) ? deg[i] : 0;
        buf[tid] = v;
        __syncthreads();
        for (int off = 1; off < 1024; off <<= 1) {
            int t = (tid >= off) ? buf[tid - off] : 0;
            __syncthreads();
            buf[tid] += t;
            __syncthreads();
        }
        int inc = buf[tid];
        if (i < n) { indptr[i + 1] = running + inc; cursor[i] = running + inc - v; }
        running += buf[1023];
        __syncthreads();
    }
    if (tid == 0) indptr[0] = 0;
}

__global__ void scatter_kernel(const int* __restrict__ src, const int* __restrict__ dst,
                               int* __restrict__ cursor, int* __restrict__ csr_src, int n) {
    int e = blockIdx.x * blockDim.x + threadIdx.x;
    if (e < n) {
        int d = dst[e];
        if (d < 0 || d >= GN) return;
        int p = atomicAdd(&cursor[d], 1);
        if (p >= 0 && p < GE) csr_src[p] = src[e];
    }
}

// ---------------- w transpose: w[128][M] -> wt[M][128] (bf16 bits out) ----------------
__global__ void transpose_w(const void* __restrict__ w, unsigned short* __restrict__ wt, int M,
                            const int* __restrict__ flag) {
    int m = (*flag != 0) ? 1 : 0;
    int idx = blockIdx.x * blockDim.x + threadIdx.x;
    if (idx < 128 * M) {
        int k = idx / M, c = idx - k * M;
        wt[c * 128 + k] = f2bfu(ldx(w, idx, m));
    }
}

// ---------------- GEMM: Y[N,M](bf16) = X[N,128] @ W[128,M], fp32 acc ----------------
__global__ __launch_bounds__(256) void gemm_tile(const void* __restrict__ X, int xext,
                                                 const void* __restrict__ W,
                                                 bf16* __restrict__ Y, int nrows, int M,
                                                 const int* __restrict__ flag) {
    __shared__ float Xs[128][68];           // [k][r], pad to spread banks
    __shared__ unsigned short Ws[128][64];  // [k][c] bf16 bits
    int m = (*flag != 0) ? 1 : 0;
    int mx_ = xext ? m : 0;
    int tid = threadIdx.x;
    int rb = blockIdx.x * 64;
    int cb = blockIdx.y * 64;

    for (int idx = tid; idx < 64 * 128; idx += 256) {
        int r = idx >> 7, k = idx & 127;
        int row = rb + r;
        Xs[k][r] = (row < nrows) ? ldx(X, (size_t)row * 128 + k, mx_) : 0.f;
    }
    for (int idx = tid; idx < 128 * 64; idx += 256) {
        int k = idx >> 6, c = idx & 63;
        int col = cb + c;
        Ws[k][c] = (col < M) ? f2bfu(ldx(W, (size_t)k * M + col, m)) : (unsigned short)0;
    }
    __syncthreads();

    int cx = (tid & 15) << 2;
    int ry = (tid >> 4) << 2;
    float acc[4][4] = {};
#pragma unroll 4
    for (int k = 0; k < 128; k++) {
        float4 xv = *(const float4*)&Xs[k][ry];
        ushort4 wv = *(const ushort4*)&Ws[k][cx];
        float xs[4] = {xv.x, xv.y, xv.z, xv.w};
        float ws[4] = {__uint_as_float((unsigned)wv.x << 16), __uint_as_float((unsigned)wv.y << 16),
                       __uint_as_float((unsigned)wv.z << 16), __uint_as_float((unsigned)wv.w << 16)};
#pragma unroll
        for (int i = 0; i < 4; i++)
#pragma unroll
            for (int j = 0; j < 4; j++) acc[i][j] += xs[i] * ws[j];
    }
#pragma unroll
    for (int i = 0; i < 4; i++) {
        int row = rb + ry + i;
        if (row >= nrows) break;
#pragma unroll
        for (int j = 0; j < 4; j++) {
            int col = cb + cx + j;
            if (col < M) Y[(size_t)row * M + col] = __float2bfloat16(acc[i][j]);
        }
    }
}

// ---------------- in-place GEMM: X[nrows,128] <- X @ W[128,128] ----------------
// Each block owns 64 rows exclusively: stages them to LDS, then overwrites them.
__global__ __launch_bounds__(256) void gemm_inplace(bf16* __restrict__ X,
                                                    const void* __restrict__ W, int nrows,
                                                    const int* __restrict__ flag) {
    __shared__ float Xs[64][132];
    __shared__ unsigned short Ws[128][128];
    int m = (*flag != 0) ? 1 : 0;
    int tid = threadIdx.x;
    int rb = blockIdx.x * 64;

    for (int idx = tid; idx < 64 * 128; idx += 256) {
        int r = idx >> 7, k = idx & 127;
        int row = rb + r;
        Xs[r][k] = (row < nrows) ? __bfloat162float(X[(size_t)row * 128 + k]) : 0.f;
    }
    for (int idx = tid; idx < 128 * 128; idx += 256) {
        int k = idx >> 7, c = idx & 127;
        Ws[k][c] = f2bfu(ldx(W, (size_t)k * 128 + c, m));
    }
    __syncthreads();

    int cx = (tid & 31) << 2;  // 0..124
    int ry = (tid >> 5) << 3;  // 0..56
    float acc[8][4] = {};
    for (int k = 0; k < 128; k++) {
        float ws[4];
        ws[0] = __uint_as_float((unsigned)Ws[k][cx] << 16);
        ws[1] = __uint_as_float((unsigned)Ws[k][cx + 1] << 16);
        ws[2] = __uint_as_float((unsigned)Ws[k][cx + 2] << 16);
        ws[3] = __uint_as_float((unsigned)Ws[k][cx + 3] << 16);
#pragma unroll
        for (int i = 0; i < 8; i++) {
            float xv = Xs[ry + i][k];
#pragma unroll
            for (int j = 0; j < 4; j++) acc[i][j] += xv * ws[j];
        }
    }
#pragma unroll
    for (int i = 0; i < 8; i++) {
        int row = rb + ry + i;
        if (row >= nrows) break;
#pragma unroll
        for (int j = 0; j < 4; j++)
            X[(size_t)row * 128 + cx + j] = __float2bfloat16(acc[i][j]);
    }
}

// ---------------- el/er: [N,H] dot over F ----------------
__global__ void elr_kernel(const bf16* __restrict__ ft, const void* __restrict__ al,
                           const void* __restrict__ ar, float* __restrict__ el,
                           float* __restrict__ er, int n, int F, const int* __restrict__ flag) {
    int m = (*flag != 0) ? 1 : 0;
    int gid = blockIdx.x * blockDim.x + threadIdx.x;
    if (gid >= n * 4) return;
    int nid = gid >> 2, h = gid & 3;
    const bf16* f = ft + (size_t)nid * (4 * F) + h * F;
    float sl = 0.f, sr = 0.f;
    for (int i = 0; i < F; i++) {
        float v = __bfloat162float(f[i]);
        sl += v * ldx(al, h * F + i, m);
        sr += v * ldx(ar, h * F + i, m);
    }
    el[gid] = sl;
    er[gid] = sr;
}

// ---------------- per-dst softmax + aggregation ----------------
// skip_pre != nullptr: skip precomputed (read own row v).
// else: fused matvec from h_in using TRANSPOSED weights wt[FTOT][128] (bf16 bits),
//       thread t reads its own contiguous 256B row -> 16 x uint4 loads.
// out may alias skip_pre / h_in buffer: block v reads only row v, writes row v last.
template <int FTOT, bool FINAL>
__global__ __launch_bounds__(128) void agg_kernel(
    const bf16* __restrict__ ft, const float* __restrict__ el, const float* __restrict__ er,
    const int* __restrict__ indptr, const int* __restrict__ csr_src,
    const void* __restrict__ bias, const void* __restrict__ h_in, int hext,
    const unsigned short* __restrict__ wt, const bf16* __restrict__ skip_pre,
    bf16* __restrict__ out, const void* __restrict__ bias_last, void* __restrict__ fout,
    const int* __restrict__ flag) {
    constexpr int F = FTOT / 4;
    constexpr int CH = 128;
    int m = (*flag != 0) ? 1 : 0;
    int mh = hext ? m : 0;
    int v = blockIdx.x;
    int t = threadIdx.x;
    int beg = indptr[v], end = indptr[v + 1];
    beg = max(0, min(beg, GE));
    end = max(beg, min(end, GE));

    __shared__ float hv[128];
    __shared__ float wbuf[CH * 4];
    __shared__ int ubuf[CH];
    __shared__ float red[128];
    __shared__ float s_sh[4];
    __shared__ float ovals[FINAL ? 160 : 1];
    __shared__ float lsm[FINAL ? 64 : 1];

    float sk0 = 0.f, sk1 = 0.f;
    if (skip_pre != nullptr) {
        sk0 = __bfloat162float(skip_pre[(size_t)v * FTOT + t]);
    } else {
        hv[t] = ldx(h_in, (size_t)v * 128 + t, mh);
        __syncthreads();
        // skip = h[v] @ w_lin via transposed weights: contiguous 16B loads per thread
        const unsigned short* wr = wt + (size_t)t * 128;
        float p0 = 0.f, p1 = 0.f, p2 = 0.f, p3 = 0.f;
#pragma unroll 2
        for (int kb = 0; kb < 128; kb += 8) {
            uint4 wv = *(const uint4*)(wr + kb);
            float4 hA = *(const float4*)&hv[kb];
            float4 hB = *(const float4*)&hv[kb + 4];
            p0 += hA.x * lo16(wv.x) + hA.y * hi16(wv.x);
            p1 += hA.z * lo16(wv.y) + hA.w * hi16(wv.y);
            p2 += hB.x * lo16(wv.z) + hB.y * hi16(wv.z);
            p3 += hB.z * lo16(wv.w) + hB.w * hi16(wv.w);
        }
        sk0 = (p0 + p1) + (p2 + p3);
        if (FTOT > 128 && t < FTOT - 128) {
            const unsigned short* wr2 = wt + (size_t)(128 + t) * 128;
            float q0 = 0.f, q1 = 0.f, q2 = 0.f, q3 = 0.f;
#pragma unroll 2
            for (int kb = 0; kb < 128; kb += 8) {
                uint4 wv = *(const uint4*)(wr2 + kb);
                float4 hA = *(const float4*)&hv[kb];
                float4 hB = *(const float4*)&hv[kb + 4];
                q0 += hA.x * lo16(wv.x) + hA.y * hi16(wv.x);
                q1 += hA.z * lo16(wv.y) + hA.w * hi16(wv.y);
                q2 += hB.x * lo16(wv.z) + hB.y * hi16(wv.z);
                q3 += hB.z * lo16(wv.w) + hB.w * hi16(wv.w);
            }
            sk1 = (q0 + q1) + (q2 + q3);
        }
    }

    int h = t & 3, slot = t >> 2;
    float erv = er[v * 4 + h];
    float s_part = 0.f, acc0 = 0.f, acc1 = 0.f;
    int h0 = t / F;

    for (int cb = beg; cb < end; cb += CH) {
        int chn = min(CH, end - cb);
        for (int j = slot; j < chn; j += 32) {
            int u = csr_src[cb + j];
            u = min(max(u, 0), GN - 1);
            if (h == 0) ubuf[j] = u;
            float e = el[u * 4 + h] + erv;
            e = e > 0.f ? e : 0.2f * e;
            float w = __expf(fminf(e, 60.f));
            wbuf[j * 4 + h] = w;
            s_part += w;
        }
        __syncthreads();
        for (int j = 0; j < chn; j++) {
            int u = ubuf[j];
            const bf16* fu = ft + (size_t)u * FTOT;
            acc0 += wbuf[j * 4 + h0] * __bfloat162float(fu[t]);
            if (FTOT > 128 && t < FTOT - 128)
                acc1 += wbuf[j * 4 + 3] * __bfloat162float(fu[128 + t]);
        }
        __syncthreads();
    }

    red[t] = s_part;
    __syncthreads();
    for (int off = 64; off >= 4; off >>= 1) {
        if (t < off) red[t] += red[t + off];
        __syncthreads();
    }
    if (t < 4) s_sh[t] = red[t];
    __syncthreads();

    float s0 = s_sh[h0];
    float r0 = (s0 > 0.f) ? acc0 / s0 : 0.f;
    float o0 = r0 + ldx(bias, t, m) + sk0;
    float o1 = 0.f;
    if (FTOT > 128 && t < FTOT - 128) {
        float s1 = s_sh[3];
        float r1 = (s1 > 0.f) ? acc1 / s1 : 0.f;
        o1 = r1 + ldx(bias, 128 + t, m) + sk1;
    }

    if constexpr (!FINAL) {
        out[(size_t)v * FTOT + t] = __float2bfloat16(guard_finite(o0));
    } else {
        ovals[t] = o0;
        if (t < 32) ovals[128 + t] = o1;
        __syncthreads();
        if (t < 40)
            lsm[t] = 0.25f * (ovals[t] + ovals[40 + t] + ovals[80 + t] + ovals[120 + t]) +
                     ldx(bias_last, t, m);
        __syncthreads();
        if (t < 64) {
            float x = (t < 40) ? lsm[t] : -3.0e38f;
            float mx = x;
            for (int off = 1; off < 64; off <<= 1) mx = fmaxf(mx, __shfl_xor(mx, off));
            float ex = (t < 40) ? __expf(x - mx) : 0.f;
            float sum = ex;
            for (int off = 1; off < 64; off <<= 1) sum += __shfl_xor(sum, off);
            if (t < 40) stx(fout, (size_t)v * 40 + t, m, guard_finite(x - mx - __logf(sum)));
        }
    }
}

// ---------------- BatchNorm (+ ReLU) on bf16 [N,128] ----------------
__global__ void bn_stats(const bf16* __restrict__ x, float* __restrict__ gsum,
                         float* __restrict__ gsq, int n) {
    int c = threadIdx.x;  // 128
    int rows_per_block = (n + gridDim.x - 1) / gridDim.x;
    int r0 = blockIdx.x * rows_per_block;
    int r1 = min(n, r0 + rows_per_block);
    float s = 0.f, q = 0.f;
    for (int r = r0; r < r1; r++) {
        float v = __bfloat162float(x[(size_t)r * 128 + c]);
        s += v;
        q += v * v;
    }
    atomicAdd(&gsum[c], s);
    atomicAdd(&gsq[c], q);
}

__global__ void bn_apply(bf16* __restrict__ x, const float* __restrict__ gsum,
                         const float* __restrict__ gsq, const void* __restrict__ g,
                         const void* __restrict__ be, int n, const int* __restrict__ flag) {
    int m = (*flag != 0) ? 1 : 0;
    int gid = blockIdx.x * blockDim.x + threadIdx.x;
    if (gid >= n * 128) return;
    int c = gid & 127;
    float inv_n = 1.f / (float)n;
    float mu = gsum[c] * inv_n;
    float var = gsq[c] * inv_n - mu * mu;
    float y = (__bfloat162float(x[gid]) - mu) * rsqrtf(fmaxf(var, 0.f) + 1e-5f) * ldx(g, c, m) +
              ldx(be, c, m);
    x[gid] = __float2bfloat16(y > 0.f ? y : 0.f);
}

extern "C" void kernel_launch(void* const* d_in, const int* in_sizes, int n_in,
                              void* d_out, int out_size, void* d_ws, size_t ws_size,
                              hipStream_t stream) {
    const void* feat = d_in[0];
    const int* src = (const int*)d_in[1];
    const int* dst = (const int*)d_in[2];
    const void* w_fc0 = d_in[3];
    const void* al0 = d_in[4];
    const void* ar0 = d_in[5];
    const void* b0 = d_in[6];
    const void* w_lin0 = d_in[7];
    const void* g0 = d_in[8];
    const void* be0 = d_in[9];
    const void* w_fc1 = d_in[10];
    const void* al1 = d_in[11];
    const void* ar1 = d_in[12];
    const void* b1 = d_in[13];
    const void* w_lin1 = d_in[14];
    const void* g1 = d_in[15];
    const void* be1 = d_in[16];
    const void* w_fc2 = d_in[17];
    const void* al2 = d_in[18];
    const void* ar2 = d_in[19];
    const void* b2 = d_in[20];
    const void* w_lin2 = d_in[21];
    const void* bias_last = d_in[22];

    // ---- workspace guard: total need ~34.4 MB ----
    if (ws_size < 35000000) {
        sentinel_kernel<<<(out_size + 255) / 256, 256, 0, stream>>>((unsigned short*)d_out,
                                                                    out_size);
        return;
    }

    char* p = (char*)d_ws;
    auto alloc = [&](size_t bytes) {
        char* r = p;
        p += (bytes + 255) & ~(size_t)255;
        return r;
    };
    bf16* ftb = (bf16*)alloc((size_t)GN * 160 * 2);   // 16.0 MB
    bf16* hbuf = (bf16*)alloc((size_t)GN * 128 * 2);  // 12.8 MB
    float* elb = (float*)alloc((size_t)GN * 4 * 4);   // 0.8 MB
    float* erb = (float*)alloc((size_t)GN * 4 * 4);   // 0.8 MB
    int* indptr = (int*)alloc((size_t)(GN + 1) * 4);
    int* cursor = (int*)alloc((size_t)GN * 4);
    unsigned short* wt2 = (unsigned short*)alloc(160 * 128 * 2);  // 40 KB
    char* zbase = p;  // ---- zero-initialized region ----
    int* deg = (int*)alloc((size_t)GN * 4);
    int* csr = (int*)alloc((size_t)GE * 4);  // 3.2 MB
    float* gs0 = (float*)alloc(128 * 4);
    float* gq0 = (float*)alloc(128 * 4);
    float* gs1 = (float*)alloc(128 * 4);
    float* gq1 = (float*)alloc(128 * 4);
    int* flag = (int*)alloc(4);
    hipMemsetAsync(zbase, 0, (size_t)(p - zbase), stream);

    detect_kernel<<<1, 256, 0, stream>>>((const unsigned short*)feat, flag);

    // CSR build + weight transpose (independent, early)
    count_kernel<<<(GE + 255) / 256, 256, 0, stream>>>(dst, deg, GE);
    scan_kernel<<<1, 1024, 0, stream>>>(deg, indptr, cursor, GN);
    scatter_kernel<<<(GE + 255) / 256, 256, 0, stream>>>(src, dst, cursor, csr, GE);
    transpose_w<<<80, 256, 0, stream>>>(w_lin2, wt2, 160, flag);

    dim3 g2(782, 2), g3(782, 3);

    // ----- Layer 0 -----
    gemm_tile<<<g2, 256, 0, stream>>>(feat, 1, w_fc0, ftb, GN, 128, flag);
    gemm_tile<<<g2, 256, 0, stream>>>(feat, 1, w_lin0, hbuf, GN, 128, flag);  // skip0 -> hbuf
    elr_kernel<<<(GN * 4 + 255) / 256, 256, 0, stream>>>(ftb, al0, ar0, elb, erb, GN, 32, flag);
    agg_kernel<128, false><<<GN, 128, 0, stream>>>(ftb, elb, erb, indptr, csr, b0, feat, 1,
                                                   nullptr, hbuf, hbuf, nullptr, nullptr, flag);
    bn_stats<<<256, 128, 0, stream>>>(hbuf, gs0, gq0, GN);
    bn_apply<<<(GN * 128 + 255) / 256, 256, 0, stream>>>(hbuf, gs0, gq0, g0, be0, GN, flag);

    // ----- Layer 1 (h updated in place) -----
    gemm_tile<<<g2, 256, 0, stream>>>(hbuf, 0, w_fc1, ftb, GN, 128, flag);
    elr_kernel<<<(GN * 4 + 255) / 256, 256, 0, stream>>>(ftb, al1, ar1, elb, erb, GN, 32, flag);
    gemm_inplace<<<782, 256, 0, stream>>>(hbuf, w_lin1, GN, flag);  // hbuf <- h1 @ w_lin1
    agg_kernel<128, false><<<GN, 128, 0, stream>>>(ftb, elb, erb, indptr, csr, b1, hbuf, 0,
                                                   nullptr, hbuf, hbuf, nullptr, nullptr, flag);
    bn_stats<<<256, 128, 0, stream>>>(hbuf, gs1, gq1, GN);
    bn_apply<<<(GN * 128 + 255) / 256, 256, 0, stream>>>(hbuf, gs1, gq1, g1, be1, GN, flag);

    // ----- Layer 2 (final; skip matvec via transposed weights) -----
    gemm_tile<<<g3, 256, 0, stream>>>(hbuf, 0, w_fc2, ftb, GN, 160, flag);
    elr_kernel<<<(GN * 4 + 255) / 256, 256, 0, stream>>>(ftb, al2, ar2, elb, erb, GN, 40, flag);
    agg_kernel<160, true><<<GN, 128, 0, stream>>>(ftb, elb, erb, indptr, csr, b2, hbuf, 0,
                                                  wt2, nullptr, nullptr, bias_last, d_out, flag);
}